// Round 10
// baseline (213.321 us; speedup 1.0000x reference)
//
#include <hip/hip_runtime.h>
#include <math.h>

#define B  8
#define T  16
#define C  64
#define H  56
#define W  56
#define HW (H*W)          // 3136
#define HW4 (HW/4)        // 784
#define DS 8
#define DIN (DS*DS)       // 64
#define DOUT 32
#define BC (B*C)          // 512

typedef float vfloat4 __attribute__((ext_vector_type(4)));

// ---------------------------------------------------------------------------
// R9 -> R10: apply time is invariant (~60 us) across 5 ILP/MLP/TLP variants
// while pool (5.7 TB/s) and fills (6.7 TB/s) run near peak -> the remaining
// suspect is the memory-system shape of apply's streams (16 strided streams,
// 1.8-4 KB granule, zero inter-block locality). New apply: block per n with
// 1024 threads (16 waves, 2 blocks/CU = 32 waves/CU HW max). Per block:
// reads its 200 KB x-slice as 16 CONTIGUOUS 12.5 KB runs (each line touched
// 2x, second touch L2-hit in a tight window), writes 16 contiguous 12.5 KB
// runs. Waves: half 0 -> t 0..7, half 1 -> t 8..15; 512 lanes sweep 784
// float4 cols. K1/K2 unchanged.
// ---------------------------------------------------------------------------

// K1: pool. Block per (n,t): 8192 blocks x 256 thr, 13.5 KB LDS.
// ~18 us ~= its 16 us HBM floor (5.7 TB/s). Wave-uniform 7x7 reduce.
__global__ __launch_bounds__(256) void pool_kernel(const float* __restrict__ x,
                                                   float* __restrict__ pooled_g) {
    __shared__ float xs[HW];      // 12544 B
    __shared__ float part[256];   // 1 KB
    const int n = blockIdx.x;     // b*C + c
    const int t = blockIdx.y;
    const int tid = threadIdx.x;
    const int b = n >> 6;
    const int c = n & 63;

    const float4* x4 = (const float4*)x;
    float4* xs4 = (float4*)xs;
    const size_t base = ((size_t)(b * T + t) * C + c) * HW4;

    for (int i = tid; i < HW4; i += 256) xs4[i] = x4[base + i];
    __syncthreads();

    {
        const int wi = tid & 63;      // window = ri*8+rj
        const int q  = tid >> 6;      // wave index -> row group (uniform)
        const int ri = wi >> 3;
        const int rj = wi & 7;
        const int r0 = 2 * q;
        const int nrows = (q < 3) ? 2 : 1;
        float s = 0.f;
        for (int dr = 0; dr < nrows; ++dr) {
            const int row = 7 * ri + r0 + dr;
            const int col0 = 7 * rj;
            #pragma unroll
            for (int dj = 0; dj < 7; ++dj) s += xs[row * W + col0 + dj];
        }
        part[q * 64 + wi] = s;
    }
    __syncthreads();

    if (tid < 64) {
        const float v = part[tid] + part[tid + 64] + part[tid + 128] + part[tid + 192];
        pooled_g[((size_t)n * T + t) * DIN + tid] = v * (1.0f / 49.0f);
    }
}

// K2: q/k + logits + softmax per n. 512 blocks x 256 thr (glue, ~4 us;
// inputs L2/L3-hot). Writes att TRANSPOSED: att_g[n][s*16+t].
__global__ __launch_bounds__(256) void att_kernel(const float* __restrict__ pooled_g,
                                                  const float* __restrict__ Wq,
                                                  const float* __restrict__ bq,
                                                  const float* __restrict__ Wk,
                                                  const float* __restrict__ bk,
                                                  float* __restrict__ att_g) {
    __shared__ float pooled_s[T * DIN];   // 4 KB
    __shared__ float qs[T * 33];
    __shared__ float ks[T * 33];
    __shared__ float att_s[T * T];

    const int n = blockIdx.x;
    const int tid = threadIdx.x;

    for (int e = tid; e < T * DIN; e += 256) pooled_s[e] = pooled_g[(size_t)n * (T * DIN) + e];
    __syncthreads();

    for (int e = tid; e < T * DOUT; e += 256) {
        const int t = e >> 5;
        const int d = e & 31;
        float sq = bq[d];
        float sk = bk[d];
        #pragma unroll 8
        for (int kk = 0; kk < DIN; ++kk) {
            const float f = pooled_s[t * DIN + kk];
            sq = fmaf(f, Wq[kk * DOUT + d], sq);
            sk = fmaf(f, Wk[kk * DOUT + d], sk);
        }
        qs[t * 33 + d] = sq;
        ks[t * 33 + d] = sk;
    }
    __syncthreads();

    {
        const int tt = tid >> 4;
        const int ss = tid & 15;
        float s = 0.f;
        #pragma unroll
        for (int d = 0; d < DOUT; ++d) s = fmaf(qs[tt * 33 + d], ks[ss * 33 + d], s);
        att_s[tid] = s * 0.25f;           // 1/sqrt(16)
    }
    __syncthreads();

    if (tid < T) {
        const int r = tid;
        float m = -INFINITY;
        #pragma unroll
        for (int s = 0; s < T; ++s) m = fmaxf(m, att_s[r * T + s]);
        float e[T];
        float sum = 0.f;
        #pragma unroll
        for (int s = 0; s < T; ++s) { e[s] = __expf(att_s[r * T + s] - m); sum += e[s]; }
        const float inv = 1.0f / sum;
        #pragma unroll
        for (int s = 0; s < T; ++s) att_g[(size_t)n * (T * T) + s * T + r] = e[s] * inv;  // transposed
    }
}

// K3: apply. Block per n, 1024 thr (16 waves) -> 2 blocks/CU, 32 waves/CU.
// half = tid>>9 owns t-range half*8..half*8+7; inner = tid&511 sweeps the
// 784 float4 cols (2 rounds: 512 + 272 masked). Per block all global
// accesses form 16 contiguous 12.5 KB runs (reads AND writes); each x line
// is touched by both halves within a tight window -> 1 HBM fetch + 1 L2 hit.
// att panel (1 KB) broadcast from LDS as ds_read_b128.
__global__ __launch_bounds__(1024, 4) void apply_kernel(const float* __restrict__ x,
                                                        const float* __restrict__ att_g,
                                                        float* __restrict__ out) {
    __shared__ float att_lds[T * T];      // transposed [s][t], 1 KB
    const int n = blockIdx.x;             // b*C + c
    const int tid = threadIdx.x;
    const int b = n >> 6;
    const int c = n & 63;

    if (tid < 256) att_lds[tid] = att_g[(size_t)n * 256 + tid];
    __syncthreads();

    const int half  = tid >> 9;           // 0: t 0..7, 1: t 8..15
    const int inner = tid & 511;          // column worker within half
    const int q0 = half * 2;              // att4 quad pair for this half
    const float4* att4 = (const float4*)att_lds;   // att4[s*4+q] = att[t=4q..4q+3][s]

    const float4* x4 = (const float4*)x;
    float4* o4 = (float4*)out;
    const size_t base = ((size_t)(b * T) * C + c) * HW4;   // + t*tstr + col
    const size_t tstr = (size_t)C * HW4;                   // 50176 float4

    #pragma unroll 1
    for (int col = inner; col < HW4; col += 512) {
        float4 acc[8];
        #pragma unroll
        for (int j = 0; j < 8; ++j) acc[j] = make_float4(0.f, 0.f, 0.f, 0.f);

        #pragma unroll 2
        for (int s = 0; s < T; ++s) {
            const float4 xv = x4[base + (size_t)s * tstr + col];
            const float4 a0 = att4[s * 4 + q0];       // t = half*8 + 0..3
            const float4 a1 = att4[s * 4 + q0 + 1];   // t = half*8 + 4..7
            acc[0].x = fmaf(a0.x, xv.x, acc[0].x);
            acc[0].y = fmaf(a0.x, xv.y, acc[0].y);
            acc[0].z = fmaf(a0.x, xv.z, acc[0].z);
            acc[0].w = fmaf(a0.x, xv.w, acc[0].w);
            acc[1].x = fmaf(a0.y, xv.x, acc[1].x);
            acc[1].y = fmaf(a0.y, xv.y, acc[1].y);
            acc[1].z = fmaf(a0.y, xv.z, acc[1].z);
            acc[1].w = fmaf(a0.y, xv.w, acc[1].w);
            acc[2].x = fmaf(a0.z, xv.x, acc[2].x);
            acc[2].y = fmaf(a0.z, xv.y, acc[2].y);
            acc[2].z = fmaf(a0.z, xv.z, acc[2].z);
            acc[2].w = fmaf(a0.z, xv.w, acc[2].w);
            acc[3].x = fmaf(a0.w, xv.x, acc[3].x);
            acc[3].y = fmaf(a0.w, xv.y, acc[3].y);
            acc[3].z = fmaf(a0.w, xv.z, acc[3].z);
            acc[3].w = fmaf(a0.w, xv.w, acc[3].w);
            acc[4].x = fmaf(a1.x, xv.x, acc[4].x);
            acc[4].y = fmaf(a1.x, xv.y, acc[4].y);
            acc[4].z = fmaf(a1.x, xv.z, acc[4].z);
            acc[4].w = fmaf(a1.x, xv.w, acc[4].w);
            acc[5].x = fmaf(a1.y, xv.x, acc[5].x);
            acc[5].y = fmaf(a1.y, xv.y, acc[5].y);
            acc[5].z = fmaf(a1.y, xv.z, acc[5].z);
            acc[5].w = fmaf(a1.y, xv.w, acc[5].w);
            acc[6].x = fmaf(a1.z, xv.x, acc[6].x);
            acc[6].y = fmaf(a1.z, xv.y, acc[6].y);
            acc[6].z = fmaf(a1.z, xv.z, acc[6].z);
            acc[6].w = fmaf(a1.z, xv.w, acc[6].w);
            acc[7].x = fmaf(a1.w, xv.x, acc[7].x);
            acc[7].y = fmaf(a1.w, xv.y, acc[7].y);
            acc[7].z = fmaf(a1.w, xv.z, acc[7].z);
            acc[7].w = fmaf(a1.w, xv.w, acc[7].w);
        }

        #pragma unroll
        for (int j = 0; j < 8; ++j) {
            const int t = half * 8 + j;
            o4[base + (size_t)t * tstr + col] = acc[j];
        }
    }
}

extern "C" void kernel_launch(void* const* d_in, const int* in_sizes, int n_in,
                              void* d_out, int out_size, void* d_ws, size_t ws_size,
                              hipStream_t stream) {
    const float* x  = (const float*)d_in[0];
    const float* Wq = (const float*)d_in[1];
    const float* bq = (const float*)d_in[2];
    const float* Wk = (const float*)d_in[3];
    const float* bk = (const float*)d_in[4];
    float* out = (float*)d_out;

    // pooled (2 MB) in the head of out (scratch until K3 overwrites; K2
    // consumes it first — stream-ordered). att (512 KB) in workspace.
    float* pooled_g = out;
    float* att_g = (float*)d_ws;

    pool_kernel<<<dim3(BC, T), dim3(256), 0, stream>>>(x, pooled_g);
    att_kernel<<<dim3(BC), dim3(256), 0, stream>>>(pooled_g, Wq, bq, Wk, bk, att_g);
    apply_kernel<<<dim3(BC), dim3(1024), 0, stream>>>(x, att_g, out);
}

// Round 11
// 208.440 us; speedup vs baseline: 1.0234x; 1.0234x over previous
//
#include <hip/hip_runtime.h>
#include <math.h>

#define B  8
#define T  16
#define C  64
#define H  56
#define W  56
#define HW (H*W)          // 3136 floats per (n,t) slice
#define HW4 (HW/4)        // 784 float4
#define CHUNK 196         // float4 per slice-chunk = 14 rows = 2 window-rows
#define NCHUNK 4
#define DIN 64
#define DOUT 32
#define BC (B*C)          // 512

// ---------------------------------------------------------------------------
// R10 -> R11: apply is invariant ~60 us across 7 variants spanning ILP/MLP/
// TLP/locality/store-mode, while write-only (fill 6.8 TB/s) and read-only
// (pool 5.7 TB/s) passes run near peak. Last untested variable: instruction-
// level R/W interleave. This kernel PHASE-SEPARATES reads and writes via
// LDS tiles: per block, alternate {pure-read burst: 50 KB x-tile -> LDS} and
// {pure compute+write burst: LDS -> acc -> contiguous global stores}.
// One fused kernel, block per n, 1024 thr, 512 blocks = exactly 2 blocks/CU
// (phases of the two resident blocks interleave to fill bubbles). x read
// once from HBM (pool pass); apply pass re-reads L3-hot. launch_bounds
// (1024,8) -> VGPR<=64 (worst phase ~30 live, no spill) -> 32 waves/CU.
// ---------------------------------------------------------------------------
__global__ __launch_bounds__(1024, 8) void fused_kernel(const float* __restrict__ x,
                                                        const float* __restrict__ Wq,
                                                        const float* __restrict__ bq,
                                                        const float* __restrict__ Wk,
                                                        const float* __restrict__ bk,
                                                        float* __restrict__ out) {
    __shared__ float xs[16 * (CHUNK * 4)];   // 16 slices x 784 floats = 50176 B
    __shared__ float part[1024];             // 4 KB pool partials
    __shared__ float pooled_s[T * DIN];      // 4 KB
    __shared__ float qs[T * 33];             // padded
    __shared__ float ksh[T * 33];
    __shared__ float att_s[T * T];           // logits
    __shared__ float att_tr[T * T];          // probs transposed [s][t]

    const int n = blockIdx.x;                // b*C + c
    const int tid = threadIdx.x;
    const int b = n >> 6;
    const int c = n & 63;

    const float4* x4 = (const float4*)x;
    float4* o4 = (float4*)out;
    float4* xs4 = (float4*)xs;
    const size_t base = ((size_t)(b * T) * C + c) * HW4;   // + s*tstr + col
    const size_t tstr = (size_t)C * HW4;                   // 50176 float4

    // ================= pass 1: pool (4 chunks of 14 rows x 16 slices) ====
    #pragma unroll 1
    for (int g = 0; g < NCHUNK; ++g) {
        // pure-read burst: 3136 float4 (16 slices x 196), contiguous per slice
        for (int i = tid; i < 16 * CHUNK; i += 1024) {
            const int s   = i / CHUNK;       // const divisor -> magic mul
            const int off = i - s * CHUNK;
            xs4[i] = x4[base + (size_t)s * tstr + g * CHUNK + off];
        }
        __syncthreads();
        // reduce: 256 windows (16 slices x 2 wrows x 8 wcols), 4 thr/window
        {
            const int q  = tid >> 8;         // row-group (K1's proven scheme)
            const int wi = tid & 255;
            const int sl = wi >> 4;
            const int w8 = wi & 15;          // wrow*8 + wcol
            const int wrow = w8 >> 3;
            const int wcol = w8 & 7;
            const int r0 = 2 * q;
            const int nr = (q < 3) ? 2 : 1;
            float s = 0.f;
            for (int dr = 0; dr < nr; ++dr) {
                const int row = wrow * 7 + r0 + dr;          // 0..13 in chunk
                const int fbase = sl * (CHUNK * 4) + row * W + wcol * 7;
                #pragma unroll
                for (int j = 0; j < 7; ++j) s += xs[fbase + j];
            }
            part[q * 256 + wi] = s;
        }
        __syncthreads();
        if (tid < 256) {
            const int sl = tid >> 4;
            const int w8 = tid & 15;
            const float v = part[tid] + part[tid + 256] + part[tid + 512] + part[tid + 768];
            pooled_s[sl * DIN + g * 16 + w8] = v * (1.0f / 49.0f);
        }
        __syncthreads();   // part reuse + xs reuse next iter
    }

    // ================= q/k + logits + softmax (in-LDS, brief) ============
    if (tid < T * DOUT) {
        const int t = tid >> 5;
        const int d = tid & 31;
        float sq = bq[d];
        float sk = bk[d];
        #pragma unroll 8
        for (int kk = 0; kk < DIN; ++kk) {
            const float f = pooled_s[t * DIN + kk];
            sq = fmaf(f, Wq[kk * DOUT + d], sq);
            sk = fmaf(f, Wk[kk * DOUT + d], sk);
        }
        qs[t * 33 + d] = sq;
        ksh[t * 33 + d] = sk;
    }
    __syncthreads();

    if (tid < T * T) {
        const int tt = tid >> 4;
        const int ss = tid & 15;
        float s = 0.f;
        #pragma unroll
        for (int d = 0; d < DOUT; ++d) s = fmaf(qs[tt * 33 + d], ksh[ss * 33 + d], s);
        att_s[tid] = s * 0.25f;              // 1/sqrt(16)
    }
    __syncthreads();

    if (tid < T) {
        const int r = tid;
        float m = -INFINITY;
        #pragma unroll
        for (int s = 0; s < T; ++s) m = fmaxf(m, att_s[r * T + s]);
        float e[T];
        float sum = 0.f;
        #pragma unroll
        for (int s = 0; s < T; ++s) { e[s] = __expf(att_s[r * T + s] - m); sum += e[s]; }
        const float inv = 1.0f / sum;
        #pragma unroll
        for (int s = 0; s < T; ++s) att_tr[s * T + r] = e[s] * inv;
    }
    __syncthreads();

    // ================= pass 2: apply (phase-separated R then W) ==========
    #pragma unroll 1
    for (int g = 0; g < NCHUNK; ++g) {
        // pure-read burst (L3-hot: pass 1 streamed x; x = 102.8 MB < LLC)
        for (int i = tid; i < 16 * CHUNK; i += 1024) {
            const int s   = i / CHUNK;
            const int off = i - s * CHUNK;
            xs4[i] = x4[base + (size_t)s * tstr + g * CHUNK + off];
        }
        __syncthreads();
        // pure compute+write burst: 3136 outputs, 3-4 per thread
        for (int i = tid; i < 16 * CHUNK; i += 1024) {
            const int t   = i / CHUNK;
            const int col = i - t * CHUNK;
            float4 a = make_float4(0.f, 0.f, 0.f, 0.f);
            #pragma unroll 4
            for (int s = 0; s < T; ++s) {
                const float w = att_tr[s * T + t];          // wave-uniform bcast
                const float4 xv = xs4[s * CHUNK + col];     // contiguous b128
                a.x = fmaf(w, xv.x, a.x);
                a.y = fmaf(w, xv.y, a.y);
                a.z = fmaf(w, xv.z, a.z);
                a.w = fmaf(w, xv.w, a.w);
            }
            o4[base + (size_t)t * tstr + g * CHUNK + col] = a;
        }
        __syncthreads();   // xs reuse next chunk
    }
}

extern "C" void kernel_launch(void* const* d_in, const int* in_sizes, int n_in,
                              void* d_out, int out_size, void* d_ws, size_t ws_size,
                              hipStream_t stream) {
    const float* x  = (const float*)d_in[0];
    const float* Wq = (const float*)d_in[1];
    const float* bq = (const float*)d_in[2];
    const float* Wk = (const float*)d_in[3];
    const float* bk = (const float*)d_in[4];
    float* out = (float*)d_out;

    fused_kernel<<<dim3(BC), dim3(1024), 0, stream>>>(x, Wq, bq, Wk, bk, out);
}